// Round 10
// baseline (1501.395 us; speedup 1.0000x reference)
//
#include <hip/hip_runtime.h>
#include <hip/hip_bf16.h>
#include <cstdint>

#define BATCH 128
#define SEQ   512
#define EMB   300
#define HID   100
#define G3    300
#define NCLS  20
#define NROWS (SEQ * BATCH)

#define M1_WORDS 614400   // 128*512*300 / 32
#define M2_WORDS 204800   // 512*128*100 / 32

typedef __attribute__((ext_vector_type(4))) float f32x4;
typedef __attribute__((ext_vector_type(8))) short s16x8;

// ---------------- threefry2x32 (JAX-compatible, verified round 1) ----------------
__host__ __device__ __forceinline__ void threefry2x32(uint32_t k0, uint32_t k1,
                                                      uint32_t x0, uint32_t x1,
                                                      uint32_t* o0, uint32_t* o1) {
  uint32_t ks2 = k0 ^ k1 ^ 0x1BD11BDAu;
  x0 += k0; x1 += k1;
#define TFR(r) { x0 += x1; x1 = (x1 << (r)) | (x1 >> (32 - (r))); x1 ^= x0; }
  TFR(13) TFR(15) TFR(26) TFR(6)  x0 += k1;  x1 += ks2 + 1u;
  TFR(17) TFR(29) TFR(16) TFR(24) x0 += ks2; x1 += k0 + 2u;
  TFR(13) TFR(15) TFR(26) TFR(6)  x0 += k0;  x1 += k1 + 3u;
  TFR(17) TFR(29) TFR(16) TFR(24) x0 += k1;  x1 += ks2 + 4u;
  TFR(13) TFR(15) TFR(26) TFR(6)  x0 += ks2; x1 += k0 + 5u;
#undef TFR
  *o0 = x0; *o1 = x1;
}

__device__ __forceinline__ uint32_t rand_bits32(uint32_t ka, uint32_t kb, uint32_t flat) {
  uint32_t a, b;
  threefry2x32(ka, kb, 0u, flat, &a, &b);
  return a ^ b;
}

__device__ __forceinline__ short f2bf(float f) {   // RNE fp32->bf16
  union { float f; uint32_t u; } c; c.f = f;
  uint32_t u = c.u;
  return (short)((u + 0x7FFFu + ((u >> 16) & 1u)) >> 16);
}

// raw barrier: LDS-only drain, no vmcnt(0)
__device__ __forceinline__ void bar_lds() {
  __asm__ __volatile__("s_waitcnt lgkmcnt(0)" ::: "memory");
  __builtin_amdgcn_s_barrier();
  __asm__ __volatile__("" ::: "memory");
}

// ---------------- K0: precompute bit-packed dropout masks [unchanged] ----------------
__global__ __launch_bounds__(256) void k_mask(uint32_t* __restrict__ M1w,
                                              uint32_t* __restrict__ M2w,
                                              uint32_t k1a, uint32_t k1b,
                                              uint32_t k2a, uint32_t k2b) {
  const int i = blockIdx.x * 256 + threadIdx.x;
  uint32_t ka, kb, base;
  uint32_t* dst;
  if (i < M1_WORDS) { ka = k1a; kb = k1b; base = (uint32_t)i * 32u; dst = M1w + i; }
  else { ka = k2a; kb = k2b; base = (uint32_t)(i - M1_WORDS) * 32u; dst = M2w + (i - M1_WORDS); }
  uint32_t w = 0u;
#pragma unroll
  for (int j = 0; j < 32; ++j) {
    uint32_t bits = rand_bits32(ka, kb, base + (uint32_t)j);
    w |= ((~bits) >> 31) << j;
  }
  *dst = w;
}

// ---------------- K0b: prep W'' A-fragments for the recurrence MFMA ----------------
// W''[r][k], r = 16*mt + 4*q + i (mt<24): i<3 -> gate i of unit u=4mt+q (u<96);
// i==3 & (4mt+q)<12 -> slot j=4mt+q: gate j%3 of unit 96+j/3. k<100: w_hh row
// 100*g+u; k==100: b_hh (bias-as-weight, pairs with constant h[100]=1); else 0.
// Stored A-frag ordered: Wp[((mt*4 + c)*64 + lane)*8 + j], lane=(quad<<4)|ml,
// row = 16mt+ml, k = 32c + 8*quad + j.
__global__ __launch_bounds__(256) void k_prep(const float* __restrict__ w_hh,
                                              const float* __restrict__ b_hh,
                                              short* __restrict__ Wp) {
  int idx = blockIdx.x * 256 + threadIdx.x;   // 0..6143
  if (idx >= 6144) return;
  int lane = idx & 63;
  int mc = idx >> 6;
  int c = mc & 3, mt = mc >> 2;
  int ml = lane & 15, quad = lane >> 4;
  int r = 16 * mt + ml;
  int q_r = (r & 15) >> 2, i_r = r & 3;
  int base4 = 4 * mt + q_r;
  int u = -1, g = 0;
  if (i_r < 3) { if (base4 < 96) { u = base4; g = i_r; } }
  else if (base4 < 12) { u = 96 + base4 / 3; g = base4 % 3; }
  short out[8];
#pragma unroll
  for (int j = 0; j < 8; ++j) {
    int k = 32 * c + 8 * quad + j;
    float v = 0.f;
    if (u >= 0) {
      if (k < 100) v = w_hh[(size_t)(100 * g + u) * HID + k];
      else if (k == 100) v = b_hh[100 * g + u];
    }
    out[j] = f2bf(v);
  }
  *(s16x8*)(Wp + (size_t)idx * 8) = *(s16x8*)out;
}

// ---------------- K1 v5: MFMA bf16 GEMM for GI [unchanged — passing] ----------------
__global__ __launch_bounds__(256) void k_gi5(const int* __restrict__ inputs,
                                             const float* __restrict__ emb,
                                             const float* __restrict__ w_ih,
                                             const float* __restrict__ b_ih,
                                             const uint32_t* __restrict__ M1w,
                                             float* __restrict__ GI) {
  __shared__ short As[128 * 40];
  __shared__ short Bs[128 * 40];
  __shared__ int idxs[128];
  const int t = threadIdx.x;
  const int s = blockIdx.x;
  const int n0 = blockIdx.y * 128;
  const int lane = t & 63, wave = t >> 6;
  const int wr = wave >> 1, wc = wave & 1;
  const int ml = lane & 15, quad = lane >> 4;
  const int row = t >> 1;
  const int half = t & 1;

  if (t < 128) idxs[t] = inputs[t * SEQ + s];
  __syncthreads();

  f32x4 acc[4][4];
#pragma unroll
  for (int i = 0; i < 4; ++i)
#pragma unroll
    for (int j = 0; j < 4; ++j) acc[i][j] = (f32x4){0.f, 0.f, 0.f, 0.f};

  const int myidx = idxs[row];
  const int nrow = n0 + row;

  for (int c = 0; c < 10; ++c) {
    const int kc = c * 32;
    const int e0 = kc + half * 16;
    float xa[16], xb[16];
#pragma unroll
    for (int j = 0; j < 16; ++j) { xa[j] = 0.f; xb[j] = 0.f; }
    if (e0 + 15 < 300) {
#pragma unroll
      for (int q4 = 0; q4 < 4; ++q4) {
        float4 v = *(const float4*)(emb + (size_t)myidx * EMB + e0 + q4 * 4);
        xa[q4 * 4 + 0] = v.x; xa[q4 * 4 + 1] = v.y; xa[q4 * 4 + 2] = v.z; xa[q4 * 4 + 3] = v.w;
      }
      if (nrow < 300) {
#pragma unroll
        for (int q4 = 0; q4 < 4; ++q4) {
          float4 v = *(const float4*)(w_ih + (size_t)nrow * EMB + e0 + q4 * 4);
          xb[q4 * 4 + 0] = v.x; xb[q4 * 4 + 1] = v.y; xb[q4 * 4 + 2] = v.z; xb[q4 * 4 + 3] = v.w;
        }
      }
    } else if (e0 < 300) {
#pragma unroll
      for (int j = 0; j < 16; ++j) {
        int e = e0 + j;
        if (e < 300) {
          xa[j] = emb[(size_t)myidx * EMB + e];
          if (nrow < 300) xb[j] = w_ih[(size_t)nrow * EMB + e];
        }
      }
    }
    uint32_t base = (uint32_t)((row * SEQ + s) * EMB + e0);
    uint32_t mb = 0;
    if (e0 < 300) {
      uint64_t mw = (uint64_t)M1w[base >> 5] | ((uint64_t)M1w[(base >> 5) + 1] << 32);
      mb = (uint32_t)(mw >> (base & 31));
    }
    short sa[16], sb[16];
#pragma unroll
    for (int j = 0; j < 16; ++j) {
      float v = ((mb >> j) & 1u) ? xa[j] * 2.f : 0.f;
      sa[j] = f2bf(v);
      sb[j] = f2bf(xb[j]);
    }
    if (c > 0) __syncthreads();
    *(s16x8*)&As[row * 40 + half * 16 + 0] = *(s16x8*)&sa[0];
    *(s16x8*)&As[row * 40 + half * 16 + 8] = *(s16x8*)&sa[8];
    *(s16x8*)&Bs[row * 40 + half * 16 + 0] = *(s16x8*)&sb[0];
    *(s16x8*)&Bs[row * 40 + half * 16 + 8] = *(s16x8*)&sb[8];
    __syncthreads();
    s16x8 af[4], bf[4];
#pragma unroll
    for (int mt = 0; mt < 4; ++mt)
      af[mt] = *(const s16x8*)&As[(wr * 64 + mt * 16 + ml) * 40 + quad * 8];
#pragma unroll
    for (int nt = 0; nt < 4; ++nt)
      bf[nt] = *(const s16x8*)&Bs[(wc * 64 + nt * 16 + ml) * 40 + quad * 8];
#pragma unroll
    for (int mt = 0; mt < 4; ++mt)
#pragma unroll
      for (int nt = 0; nt < 4; ++nt)
        acc[mt][nt] = __builtin_amdgcn_mfma_f32_16x16x32_bf16(af[mt], bf[nt], acc[mt][nt], 0, 0, 0);
  }

#pragma unroll
  for (int nt = 0; nt < 4; ++nt) {
    int n = n0 + wc * 64 + nt * 16 + ml;
    if (n < 300) {
      float bias = b_ih[n];
#pragma unroll
      for (int mt = 0; mt < 4; ++mt) {
#pragma unroll
        for (int i = 0; i < 4; ++i) {
          int brow = wr * 64 + mt * 16 + quad * 4 + i;
          GI[(size_t)(s * BATCH + brow) * G3 + n] = acc[mt][nt][i] + bias;
        }
      }
    }
  }
}

// ---------------- K2 v9: MFMA recurrence ----------------
// 8 blocks x 512 threads (8 waves). Block bg handles batch bg*16..bg*16+15.
// Per step: D[384 gate-rows][16 batch] = W''(bf16, regs) x h_ext(bf16, LDS).
// C-layout gives each lane (ml=batch, quad) the full r/z/n triplet of unit
// u=4mt+quad in regs 0..2 -> gates lane-local, fp32 h in registers, ONE
// barrier/step. Units 96..99 ride in reg3 of tiles 0..2 (wave 0, LDS scratch,
// wave-synchronous). Bias enters via k=100 column against constant h[100]=1.
__global__ __launch_bounds__(512, 1) void k_rnn9(const float* __restrict__ GI,
                                                 const short* __restrict__ Wp,
                                                 const uint8_t* __restrict__ M2,
                                                 float* __restrict__ Hd) {
  __shared__ short hbuf[2 * 16 * 136];   // [parity][ml][k], stride 136 (16B-aligned rows)
  __shared__ float scr[16 * 13];         // wave-0 extra-unit scratch
  const int t = threadIdx.x, lane = t & 63, wave = t >> 6;
  const int ml = lane & 15, quad = lane >> 4;
  const int bg = blockIdx.x;
  const int b = bg * 16 + ml;
  const int mtb = 3 * wave;
  const int u0 = 4 * (mtb + 0) + quad;
  const int u1 = 4 * (mtb + 1) + quad;
  const int u2 = 4 * (mtb + 2) + quad;
  const int ux = 96 + quad;              // wave-0 extra unit

  // 12 resident weight fragments (48 VGPR)
  const s16x8 w00 = *(const s16x8*)(Wp + (size_t)(((mtb + 0) * 4 + 0) * 64 + lane) * 8);
  const s16x8 w01 = *(const s16x8*)(Wp + (size_t)(((mtb + 0) * 4 + 1) * 64 + lane) * 8);
  const s16x8 w02 = *(const s16x8*)(Wp + (size_t)(((mtb + 0) * 4 + 2) * 64 + lane) * 8);
  const s16x8 w03 = *(const s16x8*)(Wp + (size_t)(((mtb + 0) * 4 + 3) * 64 + lane) * 8);
  const s16x8 w10 = *(const s16x8*)(Wp + (size_t)(((mtb + 1) * 4 + 0) * 64 + lane) * 8);
  const s16x8 w11 = *(const s16x8*)(Wp + (size_t)(((mtb + 1) * 4 + 1) * 64 + lane) * 8);
  const s16x8 w12 = *(const s16x8*)(Wp + (size_t)(((mtb + 1) * 4 + 2) * 64 + lane) * 8);
  const s16x8 w13 = *(const s16x8*)(Wp + (size_t)(((mtb + 1) * 4 + 3) * 64 + lane) * 8);
  const s16x8 w20 = *(const s16x8*)(Wp + (size_t)(((mtb + 2) * 4 + 0) * 64 + lane) * 8);
  const s16x8 w21 = *(const s16x8*)(Wp + (size_t)(((mtb + 2) * 4 + 1) * 64 + lane) * 8);
  const s16x8 w22 = *(const s16x8*)(Wp + (size_t)(((mtb + 2) * 4 + 2) * 64 + lane) * 8);
  const s16x8 w23 = *(const s16x8*)(Wp + (size_t)(((mtb + 2) * 4 + 3) * 64 + lane) * 8);

  // init hbuf: zeros, bias-constant h[100]=1.0 in both parities
  for (int i = t; i < 2 * 16 * 136; i += 512) {
    int k = i % 136;
    hbuf[i] = (k == 100) ? (short)0x3F80 : (short)0;
  }

  // fp32 hidden state lives here
  float h0p = 0.f, h1p = 0.f, h2p = 0.f, hxp = 0.f;

  // prime GI + masks for s=0
  const float* gi0 = GI + (size_t)b * G3;
  float cR0 = gi0[u0], cZ0 = gi0[u0 + 100], cN0 = gi0[u0 + 200];
  float cR1 = gi0[u1], cZ1 = gi0[u1 + 100], cN1 = gi0[u1 + 200];
  float cR2 = gi0[u2], cZ2 = gi0[u2 + 100], cN2 = gi0[u2 + 200];
  float cRx = 0.f, cZx = 0.f, cNx = 0.f;
  uint8_t m0 = M2[(uint32_t)(b * HID + u0) >> 3];
  uint8_t m1 = M2[(uint32_t)(b * HID + u1) >> 3];
  uint8_t m2v = M2[(uint32_t)(b * HID + u2) >> 3];
  uint8_t mxv = 0;
  if (wave == 0) {
    cRx = gi0[ux]; cZx = gi0[ux + 100]; cNx = gi0[ux + 200];
    mxv = M2[(uint32_t)(b * HID + ux) >> 3];
  }
  __syncthreads();

#define GATE(A0, A1, A2, U, HP, CR, CZ, CN, MB) { \
    float r_ = 1.f / (1.f + __expf(-((CR) + (A0)))); \
    float z_ = 1.f / (1.f + __expf(-((CZ) + (A1)))); \
    float xn_ = (CN) + r_ * (A2); \
    float e_ = __expf(2.f * fabsf(xn_)); \
    float nn_ = copysignf(1.f - 2.f / (e_ + 1.f), xn_); \
    float hn_ = (1.f - z_) * nn_ + z_ * (HP); \
    (HP) = hn_; \
    uint32_t fl_ = (uint32_t)((s * BATCH + b) * HID + (U)); \
    float hd_ = (((MB) >> (fl_ & 7)) & 1) ? hn_ * 2.f : 0.f; \
    Hd[(size_t)(b * SEQ + s) * HID + (U)] = hd_; \
    hbuf[(p ^ 1) * 2176 + ml * 136 + (U)] = f2bf(hn_); \
  }

  for (int s = 0; s < SEQ; ++s) {
    const int p = s & 1;
    const short* hb = hbuf + p * 2176 + ml * 136;
    // B-fragments: h_ext[k][batch], lane ml = batch, k = 32c + 8*quad + j
    s16x8 B0 = *(const s16x8*)(hb + 0 + 8 * quad);
    s16x8 B1 = *(const s16x8*)(hb + 32 + 8 * quad);
    s16x8 B2 = *(const s16x8*)(hb + 64 + 8 * quad);
    s16x8 B3 = *(const s16x8*)(hb + 96 + 8 * quad);

    // prefetch next step's gi + mask bytes (full-step latency slack)
    const int sn = (s + 1 < SEQ) ? s + 1 : s;
    const float* gin = GI + (size_t)(sn * BATCH + b) * G3;
    float nR0 = gin[u0], nZ0 = gin[u0 + 100], nN0 = gin[u0 + 200];
    float nR1 = gin[u1], nZ1 = gin[u1 + 100], nN1 = gin[u1 + 200];
    float nR2 = gin[u2], nZ2 = gin[u2 + 100], nN2 = gin[u2 + 200];
    uint8_t p0 = M2[(uint32_t)((sn * BATCH + b) * HID + u0) >> 3];
    uint8_t p1 = M2[(uint32_t)((sn * BATCH + b) * HID + u1) >> 3];
    uint8_t p2 = M2[(uint32_t)((sn * BATCH + b) * HID + u2) >> 3];
    float nRx = 0.f, nZx = 0.f, nNx = 0.f;
    uint8_t px = 0;
    if (wave == 0) {
      nRx = gin[ux]; nZx = gin[ux + 100]; nNx = gin[ux + 200];
      px = M2[(uint32_t)((sn * BATCH + b) * HID + ux) >> 3];
    }

    // MFMA: 3 tiles x 4 k-chunks
    f32x4 a0 = (f32x4){0.f, 0.f, 0.f, 0.f};
    f32x4 a1 = (f32x4){0.f, 0.f, 0.f, 0.f};
    f32x4 a2 = (f32x4){0.f, 0.f, 0.f, 0.f};
    a0 = __builtin_amdgcn_mfma_f32_16x16x32_bf16(w00, B0, a0, 0, 0, 0);
    a1 = __builtin_amdgcn_mfma_f32_16x16x32_bf16(w10, B0, a1, 0, 0, 0);
    a2 = __builtin_amdgcn_mfma_f32_16x16x32_bf16(w20, B0, a2, 0, 0, 0);
    a0 = __builtin_amdgcn_mfma_f32_16x16x32_bf16(w01, B1, a0, 0, 0, 0);
    a1 = __builtin_amdgcn_mfma_f32_16x16x32_bf16(w11, B1, a1, 0, 0, 0);
    a2 = __builtin_amdgcn_mfma_f32_16x16x32_bf16(w21, B1, a2, 0, 0, 0);
    a0 = __builtin_amdgcn_mfma_f32_16x16x32_bf16(w02, B2, a0, 0, 0, 0);
    a1 = __builtin_amdgcn_mfma_f32_16x16x32_bf16(w12, B2, a1, 0, 0, 0);
    a2 = __builtin_amdgcn_mfma_f32_16x16x32_bf16(w22, B2, a2, 0, 0, 0);
    a0 = __builtin_amdgcn_mfma_f32_16x16x32_bf16(w03, B3, a0, 0, 0, 0);
    a1 = __builtin_amdgcn_mfma_f32_16x16x32_bf16(w13, B3, a1, 0, 0, 0);
    a2 = __builtin_amdgcn_mfma_f32_16x16x32_bf16(w23, B3, a2, 0, 0, 0);

    // gates: lane-local triplets (gh already includes b_hh via k=100 column)
    GATE(a0[0], a0[1], a0[2], u0, h0p, cR0, cZ0, cN0, m0)
    GATE(a1[0], a1[1], a1[2], u1, h1p, cR1, cZ1, cN1, m1)
    GATE(a2[0], a2[1], a2[2], u2, h2p, cR2, cZ2, cN2, m2v)

    if (wave == 0) {   // extra units 96..99 from reg3 pad slots (wave-synchronous)
      scr[ml * 13 + 0 + quad] = a0[3];
      scr[ml * 13 + 4 + quad] = a1[3];
      scr[ml * 13 + 8 + quad] = a2[3];
      float ghr = scr[ml * 13 + 3 * quad + 0];
      float ghz = scr[ml * 13 + 3 * quad + 1];
      float ghn = scr[ml * 13 + 3 * quad + 2];
      GATE(ghr, ghz, ghn, ux, hxp, cRx, cZx, cNx, mxv)
    }

    cR0 = nR0; cZ0 = nZ0; cN0 = nN0; m0 = p0;
    cR1 = nR1; cZ1 = nZ1; cN1 = nN1; m1 = p1;
    cR2 = nR2; cZ2 = nZ2; cN2 = nN2; m2v = p2;
    cRx = nRx; cZx = nZx; cNx = nNx; mxv = px;
    bar_lds();   // the ONE barrier per step
  }
#undef GATE
}

// ---------------- K3: logits + log_softmax [unchanged] ----------------
__global__ __launch_bounds__(64) void k_out(const float* __restrict__ Hd,
                                            const float* __restrict__ w_lin,
                                            const float* __restrict__ b_lin,
                                            float* __restrict__ out) {
  __shared__ float Wl[NCLS * HID];
  __shared__ float bl[NCLS];
  const int t = threadIdx.x;
  for (int i = t; i < NCLS * HID; i += 64) Wl[i] = w_lin[i];
  if (t < NCLS) bl[t] = b_lin[t];
  __syncthreads();

  const int r0 = (blockIdx.x * 64 + t) * 4;
  float acc[4][NCLS];
#pragma unroll
  for (int r = 0; r < 4; ++r)
#pragma unroll
    for (int c = 0; c < NCLS; ++c) acc[r][c] = bl[c];

  for (int k = 0; k < HID; k += 4) {
    float4 h0 = *(const float4*)(Hd + (size_t)(r0 + 0) * HID + k);
    float4 h1 = *(const float4*)(Hd + (size_t)(r0 + 1) * HID + k);
    float4 h2 = *(const float4*)(Hd + (size_t)(r0 + 2) * HID + k);
    float4 h3 = *(const float4*)(Hd + (size_t)(r0 + 3) * HID + k);
#pragma unroll
    for (int c = 0; c < NCLS; ++c) {
      float4 w4 = *(const float4*)&Wl[c * HID + k];
      acc[0][c] += h0.x * w4.x + h0.y * w4.y + h0.z * w4.z + h0.w * w4.w;
      acc[1][c] += h1.x * w4.x + h1.y * w4.y + h1.z * w4.z + h1.w * w4.w;
      acc[2][c] += h2.x * w4.x + h2.y * w4.y + h2.z * w4.z + h2.w * w4.w;
      acc[3][c] += h3.x * w4.x + h3.y * w4.y + h3.z * w4.z + h3.w * w4.w;
    }
  }

  float lse[4];
#pragma unroll
  for (int r = 0; r < 4; ++r) {
    float mx = acc[r][0];
#pragma unroll
    for (int c = 1; c < NCLS; ++c) mx = fmaxf(mx, acc[r][c]);
    float se = 0.f;
#pragma unroll
    for (int c = 0; c < NCLS; ++c) se += __expf(acc[r][c] - mx);
    lse[r] = mx + __logf(se);
  }
  const int b = r0 >> 9, s0 = r0 & 511;
#pragma unroll
  for (int c = 0; c < NCLS; ++c) {
    float4 o = make_float4(acc[0][c] - lse[0], acc[1][c] - lse[1],
                           acc[2][c] - lse[2], acc[3][c] - lse[3]);
    *(float4*)(out + (size_t)(b * NCLS + c) * SEQ + s0) = o;
  }
}

// ---------------- host ----------------
extern "C" void kernel_launch(void* const* d_in, const int* in_sizes, int n_in,
                              void* d_out, int out_size, void* d_ws, size_t ws_size,
                              hipStream_t stream) {
  const int*   inputs = (const int*)d_in[0];
  const float* emb    = (const float*)d_in[1];
  const float* w_ih   = (const float*)d_in[2];
  const float* w_hh   = (const float*)d_in[3];
  const float* b_ih   = (const float*)d_in[4];
  const float* b_hh   = (const float*)d_in[5];
  const float* w_lin  = (const float*)d_in[6];
  const float* b_lin  = (const float*)d_in[7];
  float* out = (float*)d_out;

  float* GI = (float*)d_ws;                           // 78.6 MB
  float* Hd = GI + (size_t)NROWS * G3;                // 26.2 MB
  uint8_t* M1 = (uint8_t*)(Hd + (size_t)NROWS * HID); // 2.46 MB
  uint8_t* M2 = M1 + (size_t)M1_WORDS * 4;            // 0.82 MB
  short* Wp = (short*)(M2 + (size_t)M2_WORDS * 4);    // 96 KB

  uint32_t dk1a, dk1b, dk2a, dk2b;
  threefry2x32(0u, 42u, 0u, 0u, &dk1a, &dk1b);
  threefry2x32(0u, 42u, 0u, 1u, &dk2a, &dk2b);

  k_mask<<<(M1_WORDS + M2_WORDS) / 256, 256, 0, stream>>>(
      (uint32_t*)M1, (uint32_t*)M2, dk1a, dk1b, dk2a, dk2b);
  k_prep<<<24, 256, 0, stream>>>(w_hh, b_hh, Wp);
  k_gi5<<<dim3(512, 3), 256, 0, stream>>>(inputs, emb, w_ih, b_ih, (const uint32_t*)M1, GI);
  k_rnn9<<<8, 512, 0, stream>>>(GI, Wp, M2, Hd);
  k_out<<<256, 64, 0, stream>>>(Hd, w_lin, b_lin, out);
}

// Round 11
// 725.218 us; speedup vs baseline: 2.0703x; 2.0703x over previous
//
#include <hip/hip_runtime.h>
#include <hip/hip_bf16.h>
#include <cstdint>

#define BATCH 128
#define SEQ   512
#define EMB   300
#define HID   100
#define G3    300
#define NCLS  20
#define NROWS (SEQ * BATCH)

#define M1_WORDS 614400   // 128*512*300 / 32
#define M2_WORDS 204800   // 512*128*100 / 32

typedef __attribute__((ext_vector_type(4))) float f32x4;
typedef __attribute__((ext_vector_type(8))) short s16x8;

// ---------------- threefry2x32 (JAX-compatible, verified round 1) ----------------
__host__ __device__ __forceinline__ void threefry2x32(uint32_t k0, uint32_t k1,
                                                      uint32_t x0, uint32_t x1,
                                                      uint32_t* o0, uint32_t* o1) {
  uint32_t ks2 = k0 ^ k1 ^ 0x1BD11BDAu;
  x0 += k0; x1 += k1;
#define TFR(r) { x0 += x1; x1 = (x1 << (r)) | (x1 >> (32 - (r))); x1 ^= x0; }
  TFR(13) TFR(15) TFR(26) TFR(6)  x0 += k1;  x1 += ks2 + 1u;
  TFR(17) TFR(29) TFR(16) TFR(24) x0 += ks2; x1 += k0 + 2u;
  TFR(13) TFR(15) TFR(26) TFR(6)  x0 += k0;  x1 += k1 + 3u;
  TFR(17) TFR(29) TFR(16) TFR(24) x0 += k1;  x1 += ks2 + 4u;
  TFR(13) TFR(15) TFR(26) TFR(6)  x0 += ks2; x1 += k0 + 5u;
#undef TFR
  *o0 = x0; *o1 = x1;
}

__device__ __forceinline__ uint32_t rand_bits32(uint32_t ka, uint32_t kb, uint32_t flat) {
  uint32_t a, b;
  threefry2x32(ka, kb, 0u, flat, &a, &b);
  return a ^ b;
}

__device__ __forceinline__ short f2bf(float f) {   // RNE fp32->bf16
  union { float f; uint32_t u; } c; c.f = f;
  uint32_t u = c.u;
  return (short)((u + 0x7FFFu + ((u >> 16) & 1u)) >> 16);
}

// raw barrier: LDS-only drain, no vmcnt(0)
__device__ __forceinline__ void bar_lds() {
  __asm__ __volatile__("s_waitcnt lgkmcnt(0)" ::: "memory");
  __builtin_amdgcn_s_barrier();
  __asm__ __volatile__("" ::: "memory");
}

// ---------------- K0: precompute bit-packed dropout masks [unchanged] ----------------
__global__ __launch_bounds__(256) void k_mask(uint32_t* __restrict__ M1w,
                                              uint32_t* __restrict__ M2w,
                                              uint32_t k1a, uint32_t k1b,
                                              uint32_t k2a, uint32_t k2b) {
  const int i = blockIdx.x * 256 + threadIdx.x;
  uint32_t ka, kb, base;
  uint32_t* dst;
  if (i < M1_WORDS) { ka = k1a; kb = k1b; base = (uint32_t)i * 32u; dst = M1w + i; }
  else { ka = k2a; kb = k2b; base = (uint32_t)(i - M1_WORDS) * 32u; dst = M2w + (i - M1_WORDS); }
  uint32_t w = 0u;
#pragma unroll
  for (int j = 0; j < 32; ++j) {
    uint32_t bits = rand_bits32(ka, kb, base + (uint32_t)j);
    w |= ((~bits) >> 31) << j;
  }
  *dst = w;
}

// ---------------- K1 v6: MFMA GI GEMM, 512 threads / 8 waves (occupancy fix) ------
// Same 128(m) x 128(n) tile & numerics as k_gi5, but: wave grid 2(m) x 4(n),
// acc = 4x2 f32x4 (32 VGPR vs 64), staging split over 512 threads (4 float4
// loads/thread/chunk vs 8). More waves resident -> chunk gather latency hidden.
__global__ __launch_bounds__(512) void k_gi6(const int* __restrict__ inputs,
                                             const float* __restrict__ emb,
                                             const float* __restrict__ w_ih,
                                             const float* __restrict__ b_ih,
                                             const uint32_t* __restrict__ M1w,
                                             float* __restrict__ GI) {
  __shared__ short As[128 * 40];   // [row][k], stride 40 shorts = 80 B
  __shared__ short Bs[128 * 40];
  __shared__ int idxs[128];
  const int t = threadIdx.x;
  const int s = blockIdx.x;
  const int n0 = blockIdx.y * 128;
  const int lane = t & 63, wave = t >> 6;
  const int wr = wave & 1;        // m half (64 rows)
  const int wc = wave >> 1;       // n quarter (32 cols)
  const int ml = lane & 15, quad = lane >> 4;
  const int row = t >> 2;         // staging row 0..127
  const int kq = t & 3;           // staging k-slot (8 elements)

  if (t < 128) idxs[t] = inputs[t * SEQ + s];
  __syncthreads();

  f32x4 acc[4][2];
#pragma unroll
  for (int i = 0; i < 4; ++i)
#pragma unroll
    for (int j = 0; j < 2; ++j) acc[i][j] = (f32x4){0.f, 0.f, 0.f, 0.f};

  const int myidx = idxs[row];
  const int nrow = n0 + row;

  for (int c = 0; c < 10; ++c) {
    const int e0 = c * 32 + kq * 8;
    // ---- stage 8 elements of A (gather+dropout1+bf16) and B (w_ih+bf16) ----
    float xa[8], xb[8];
#pragma unroll
    for (int j = 0; j < 8; ++j) { xa[j] = 0.f; xb[j] = 0.f; }
    if (e0 + 7 < 300) {
#pragma unroll
      for (int q4 = 0; q4 < 2; ++q4) {
        float4 v = *(const float4*)(emb + (size_t)myidx * EMB + e0 + q4 * 4);
        xa[q4 * 4 + 0] = v.x; xa[q4 * 4 + 1] = v.y; xa[q4 * 4 + 2] = v.z; xa[q4 * 4 + 3] = v.w;
      }
      if (nrow < 300) {
#pragma unroll
        for (int q4 = 0; q4 < 2; ++q4) {
          float4 v = *(const float4*)(w_ih + (size_t)nrow * EMB + e0 + q4 * 4);
          xb[q4 * 4 + 0] = v.x; xb[q4 * 4 + 1] = v.y; xb[q4 * 4 + 2] = v.z; xb[q4 * 4 + 3] = v.w;
        }
      }
    } else if (e0 < 300) {   // ragged tail (e0=296: 4 valid)
#pragma unroll
      for (int j = 0; j < 8; ++j) {
        int e = e0 + j;
        if (e < 300) {
          xa[j] = emb[(size_t)myidx * EMB + e];
          if (nrow < 300) xb[j] = w_ih[(size_t)nrow * EMB + e];
        }
      }
    }
    // dropout1 keep-bits (8 bits; base%4==0, may straddle a word)
    uint32_t mb = 0;
    if (e0 < 300) {
      uint32_t base = (uint32_t)((row * SEQ + s) * EMB + e0);
      uint64_t mw = (uint64_t)M1w[base >> 5] | ((uint64_t)M1w[(base >> 5) + 1] << 32);
      mb = (uint32_t)(mw >> (base & 31));
    }
    short sa[8], sb[8];
#pragma unroll
    for (int j = 0; j < 8; ++j) {
      float v = ((mb >> j) & 1u) ? xa[j] * 2.f : 0.f;
      sa[j] = f2bf(v);
      sb[j] = f2bf(xb[j]);
    }
    if (c > 0) __syncthreads();   // protect previous chunk's frag reads
    *(s16x8*)&As[row * 40 + kq * 8] = *(s16x8*)&sa[0];
    *(s16x8*)&Bs[row * 40 + kq * 8] = *(s16x8*)&sb[0];
    __syncthreads();
    // ---- MFMA: 4 m-frags x 2 n-frags per wave ----
    s16x8 af[4], bf[2];
#pragma unroll
    for (int mt = 0; mt < 4; ++mt)
      af[mt] = *(const s16x8*)&As[(wr * 64 + mt * 16 + ml) * 40 + quad * 8];
#pragma unroll
    for (int nt = 0; nt < 2; ++nt)
      bf[nt] = *(const s16x8*)&Bs[(wc * 32 + nt * 16 + ml) * 40 + quad * 8];
#pragma unroll
    for (int mt = 0; mt < 4; ++mt)
#pragma unroll
      for (int nt = 0; nt < 2; ++nt)
        acc[mt][nt] = __builtin_amdgcn_mfma_f32_16x16x32_bf16(af[mt], bf[nt], acc[mt][nt], 0, 0, 0);
  }

  // ---- epilogue: C/D layout col=lane&15, row=quad*4+i ----
#pragma unroll
  for (int nt = 0; nt < 2; ++nt) {
    int n = n0 + wc * 32 + nt * 16 + ml;
    if (n < 300) {
      float bias = b_ih[n];
#pragma unroll
      for (int mt = 0; mt < 4; ++mt) {
#pragma unroll
        for (int i = 0; i < 4; ++i) {
          int brow = wr * 64 + mt * 16 + quad * 4 + i;
          GI[(size_t)(s * BATCH + brow) * G3 + n] = acc[mt][nt][i] + bias;
        }
      }
    }
  }
}

// ---------------- K2 v8: REVERTED to round-9 version (best proven: ~467 µs) --------
__global__ __launch_bounds__(1024, 4) void k_rnn8(const float* __restrict__ GI,
                                                  const float* __restrict__ w_hh,
                                                  const float* __restrict__ b_hh,
                                                  const uint8_t* __restrict__ M2,
                                                  float* __restrict__ Hd) {
  __shared__ float4 part[8][104];
  __shared__ float h_s[100];
  const int t = threadIdx.x, lane = t & 63, wave = t >> 6;
  const int q = wave >> 1, g = wave & 1;
  const int b = blockIdx.x;
  const int ulo = (lane < 36) ? lane : 35;
  const int u = g ? (64 + ulo) : lane;
  const bool dotstore = (g == 0) || (lane < 36);
  const int klo = (q < 4) ? q * 13 : 52 + (q - 4) * 12;

  const float* rowR = w_hh + (size_t)u * HID;
  const float* rowZ = w_hh + (size_t)(u + 100) * HID;
  const float* rowN = w_hh + (size_t)(u + 200) * HID;
  const float wr0 = rowR[klo + 0],  wr1 = rowR[klo + 1],  wr2 = rowR[klo + 2],
              wr3 = rowR[klo + 3],  wr4 = rowR[klo + 4],  wr5 = rowR[klo + 5],
              wr6 = rowR[klo + 6],  wr7 = rowR[klo + 7],  wr8 = rowR[klo + 8],
              wr9 = rowR[klo + 9],  wr10 = rowR[klo + 10], wr11 = rowR[klo + 11],
              wr12 = rowR[(klo + 12 < 100) ? (klo + 12) : 99];
  const float wz0 = rowZ[klo + 0],  wz1 = rowZ[klo + 1],  wz2 = rowZ[klo + 2],
              wz3 = rowZ[klo + 3],  wz4 = rowZ[klo + 4],  wz5 = rowZ[klo + 5],
              wz6 = rowZ[klo + 6],  wz7 = rowZ[klo + 7],  wz8 = rowZ[klo + 8],
              wz9 = rowZ[klo + 9],  wz10 = rowZ[klo + 10], wz11 = rowZ[klo + 11],
              wz12 = rowZ[(klo + 12 < 100) ? (klo + 12) : 99];
  const float wn0 = rowN[klo + 0],  wn1 = rowN[klo + 1],  wn2 = rowN[klo + 2],
              wn3 = rowN[klo + 3],  wn4 = rowN[klo + 4],  wn5 = rowN[klo + 5],
              wn6 = rowN[klo + 6],  wn7 = rowN[klo + 7],  wn8 = rowN[klo + 8],
              wn9 = rowN[klo + 9],  wn10 = rowN[klo + 10], wn11 = rowN[klo + 11],
              wn12 = rowN[(klo + 12 < 100) ? (klo + 12) : 99];

  const bool ew = (wave < 4) && (lane < 25);
  const int ue = wave * 25 + lane;   // 0..99 when ew
  float bR = 0.f, bZ = 0.f, bN = 0.f, gcR = 0.f, gcZ = 0.f, gcN = 0.f;
  uint8_t mc = 0;
  if (ew) {
    bR = b_hh[ue]; bZ = b_hh[100 + ue]; bN = b_hh[200 + ue];
    const float* g0 = GI + (size_t)b * G3;
    gcR = g0[ue]; gcZ = g0[100 + ue]; gcN = g0[200 + ue];
    mc = M2[(uint32_t)(b * HID + ue) >> 3];
  }

  if (t < 100) h_s[t] = 0.f;
  float hA = 0.f, hB = 0.f;
  __syncthreads();

#define RL(reg, L) __int_as_float(__builtin_amdgcn_readlane(__float_as_int(reg), (L)))
#define S1(HS, L, WR, WZ, WN) { float hk = RL(HS, L); \
    sR = fmaf(WR, hk, sR); sZ = fmaf(WZ, hk, sZ); sN = fmaf(WN, hk, sN); }
#define D12(HS, L0) \
  S1(HS, (L0) + 0,  wr0,  wz0,  wn0)  S1(HS, (L0) + 1,  wr1,  wz1,  wn1)  \
  S1(HS, (L0) + 2,  wr2,  wz2,  wn2)  S1(HS, (L0) + 3,  wr3,  wz3,  wn3)  \
  S1(HS, (L0) + 4,  wr4,  wz4,  wn4)  S1(HS, (L0) + 5,  wr5,  wz5,  wn5)  \
  S1(HS, (L0) + 6,  wr6,  wz6,  wn6)  S1(HS, (L0) + 7,  wr7,  wz7,  wn7)  \
  S1(HS, (L0) + 8,  wr8,  wz8,  wn8)  S1(HS, (L0) + 9,  wr9,  wz9,  wn9)  \
  S1(HS, (L0) + 10, wr10, wz10, wn10) S1(HS, (L0) + 11, wr11, wz11, wn11)
#define D13(HS, L0) D12(HS, L0) S1(HS, (L0) + 12, wr12, wz12, wn12)

  for (int s = 0; s < SEQ; ++s) {
    float gnR = 0.f, gnZ = 0.f, gnN = 0.f;
    uint8_t mn = 0;
    if (ew) {
      int sn = (s + 1 < SEQ) ? s + 1 : s;
      const float* gp = GI + (size_t)(sn * BATCH + b) * G3;
      gnR = gp[ue]; gnZ = gp[100 + ue]; gnN = gp[200 + ue];
      mn = M2[(uint32_t)((sn * BATCH + b) * HID + ue) >> 3];
    }

    float sR = 0.f, sZ = 0.f, sN = 0.f;
    switch (q) {
      case 0: { D13(hA, 0)  } break;
      case 1: { D13(hA, 13) } break;
      case 2: { D13(hA, 26) } break;
      case 3: { D13(hA, 39) } break;
      case 4: { D12(hA, 52) } break;
      case 5: { D12(hB, 0)  } break;
      case 6: { D12(hB, 12) } break;
      case 7: { D12(hB, 24) } break;
    }
    if (dotstore) part[q][u] = make_float4(sR, sZ, sN, 0.f);
    bar_lds();   // barrier 1: LDS drain only — no vmcnt(0)

    if (wave < 4) {
      if (lane < 25) {
        float4 p0 = part[0][ue], p1 = part[1][ue], p2 = part[2][ue], p3 = part[3][ue];
        float4 p4 = part[4][ue], p5 = part[5][ue], p6 = part[6][ue], p7 = part[7][ue];
        float hr = ((p0.x + p1.x) + (p2.x + p3.x)) + ((p4.x + p5.x) + (p6.x + p7.x)) + bR;
        float hz = ((p0.y + p1.y) + (p2.y + p3.y)) + ((p4.y + p5.y) + (p6.y + p7.y)) + bZ;
        float hn = ((p0.z + p1.z) + (p2.z + p3.z)) + ((p4.z + p5.z) + (p6.z + p7.z)) + bN;
        float r = 1.f / (1.f + __expf(-(gcR + hr)));
        float z = 1.f / (1.f + __expf(-(gcZ + hz)));
        float xn = gcN + r * hn;
        float e2 = __expf(2.f * fabsf(xn));
        float n = copysignf(1.f - 2.f / (e2 + 1.f), xn);   // overflow-safe tanh
        float hprev = h_s[ue];
        float hnew = (1.f - z) * n + z * hprev;
        uint32_t fl = (uint32_t)((s * BATCH + b) * HID + ue);
        float hd = ((mc >> (fl & 7)) & 1) ? hnew * 2.f : 0.f;
        Hd[(size_t)(b * SEQ + s) * HID + ue] = hd;   // store stays in flight
        h_s[ue] = hnew;
      }
    }
    bar_lds();   // barrier 2: LDS drain only
    hA = h_s[lane];
    hB = h_s[64 + ulo];
    gcR = gnR; gcZ = gnZ; gcN = gnN; mc = mn;
  }
#undef D13
#undef D12
#undef S1
#undef RL
}

// ---------------- K3: logits + log_softmax [unchanged] ----------------
__global__ __launch_bounds__(64) void k_out(const float* __restrict__ Hd,
                                            const float* __restrict__ w_lin,
                                            const float* __restrict__ b_lin,
                                            float* __restrict__ out) {
  __shared__ float Wl[NCLS * HID];
  __shared__ float bl[NCLS];
  const int t = threadIdx.x;
  for (int i = t; i < NCLS * HID; i += 64) Wl[i] = w_lin[i];
  if (t < NCLS) bl[t] = b_lin[t];
  __syncthreads();

  const int r0 = (blockIdx.x * 64 + t) * 4;
  float acc[4][NCLS];
#pragma unroll
  for (int r = 0; r < 4; ++r)
#pragma unroll
    for (int c = 0; c < NCLS; ++c) acc[r][c] = bl[c];

  for (int k = 0; k < HID; k += 4) {
    float4 h0 = *(const float4*)(Hd + (size_t)(r0 + 0) * HID + k);
    float4 h1 = *(const float4*)(Hd + (size_t)(r0 + 1) * HID + k);
    float4 h2 = *(const float4*)(Hd + (size_t)(r0 + 2) * HID + k);
    float4 h3 = *(const float4*)(Hd + (size_t)(r0 + 3) * HID + k);
#pragma unroll
    for (int c = 0; c < NCLS; ++c) {
      float4 w4 = *(const float4*)&Wl[c * HID + k];
      acc[0][c] += h0.x * w4.x + h0.y * w4.y + h0.z * w4.z + h0.w * w4.w;
      acc[1][c] += h1.x * w4.x + h1.y * w4.y + h1.z * w4.z + h1.w * w4.w;
      acc[2][c] += h2.x * w4.x + h2.y * w4.y + h2.z * w4.z + h2.w * w4.w;
      acc[3][c] += h3.x * w4.x + h3.y * w4.y + h3.z * w4.z + h3.w * w4.w;
    }
  }

  float lse[4];
#pragma unroll
  for (int r = 0; r < 4; ++r) {
    float mx = acc[r][0];
#pragma unroll
    for (int c = 1; c < NCLS; ++c) mx = fmaxf(mx, acc[r][c]);
    float se = 0.f;
#pragma unroll
    for (int c = 0; c < NCLS; ++c) se += __expf(acc[r][c] - mx);
    lse[r] = mx + __logf(se);
  }
  const int b = r0 >> 9, s0 = r0 & 511;
#pragma unroll
  for (int c = 0; c < NCLS; ++c) {
    float4 o = make_float4(acc[0][c] - lse[0], acc[1][c] - lse[1],
                           acc[2][c] - lse[2], acc[3][c] - lse[3]);
    *(float4*)(out + (size_t)(b * NCLS + c) * SEQ + s0) = o;
  }
}

// ---------------- host ----------------
extern "C" void kernel_launch(void* const* d_in, const int* in_sizes, int n_in,
                              void* d_out, int out_size, void* d_ws, size_t ws_size,
                              hipStream_t stream) {
  const int*   inputs = (const int*)d_in[0];
  const float* emb    = (const float*)d_in[1];
  const float* w_ih   = (const float*)d_in[2];
  const float* w_hh   = (const float*)d_in[3];
  const float* b_ih   = (const float*)d_in[4];
  const float* b_hh   = (const float*)d_in[5];
  const float* w_lin  = (const float*)d_in[6];
  const float* b_lin  = (const float*)d_in[7];
  float* out = (float*)d_out;

  float* GI = (float*)d_ws;                           // 78.6 MB
  float* Hd = GI + (size_t)NROWS * G3;                // 26.2 MB
  uint8_t* M1 = (uint8_t*)(Hd + (size_t)NROWS * HID); // 2.46 MB
  uint8_t* M2 = M1 + (size_t)M1_WORDS * 4;            // 0.82 MB

  uint32_t dk1a, dk1b, dk2a, dk2b;
  threefry2x32(0u, 42u, 0u, 0u, &dk1a, &dk1b);
  threefry2x32(0u, 42u, 0u, 1u, &dk2a, &dk2b);

  k_mask<<<(M1_WORDS + M2_WORDS) / 256, 256, 0, stream>>>(
      (uint32_t*)M1, (uint32_t*)M2, dk1a, dk1b, dk2a, dk2b);
  k_gi6<<<dim3(512, 3), 512, 0, stream>>>(inputs, emb, w_ih, b_ih, (const uint32_t*)M1, GI);
  k_rnn8<<<BATCH, 1024, 0, stream>>>(GI, w_hh, b_hh, M2, Hd);
  k_out<<<256, 64, 0, stream>>>(Hd, w_lin, b_lin, out);
}

// Round 12
// 700.872 us; speedup vs baseline: 2.1422x; 1.0347x over previous
//
#include <hip/hip_runtime.h>
#include <hip/hip_bf16.h>
#include <cstdint>

#define BATCH 128
#define SEQ   512
#define EMB   300
#define HID   100
#define G3    300
#define NCLS  20
#define NROWS (SEQ * BATCH)

#define M1_WORDS 614400   // 128*512*300 / 32
#define M2_WORDS 204800   // 512*128*100 / 32

typedef __attribute__((ext_vector_type(4))) float f32x4;
typedef __attribute__((ext_vector_type(8))) short s16x8;

// ---------------- threefry2x32 (JAX-compatible, verified round 1) ----------------
__host__ __device__ __forceinline__ void threefry2x32(uint32_t k0, uint32_t k1,
                                                      uint32_t x0, uint32_t x1,
                                                      uint32_t* o0, uint32_t* o1) {
  uint32_t ks2 = k0 ^ k1 ^ 0x1BD11BDAu;
  x0 += k0; x1 += k1;
#define TFR(r) { x0 += x1; x1 = (x1 << (r)) | (x1 >> (32 - (r))); x1 ^= x0; }
  TFR(13) TFR(15) TFR(26) TFR(6)  x0 += k1;  x1 += ks2 + 1u;
  TFR(17) TFR(29) TFR(16) TFR(24) x0 += ks2; x1 += k0 + 2u;
  TFR(13) TFR(15) TFR(26) TFR(6)  x0 += k0;  x1 += k1 + 3u;
  TFR(17) TFR(29) TFR(16) TFR(24) x0 += k1;  x1 += ks2 + 4u;
  TFR(13) TFR(15) TFR(26) TFR(6)  x0 += ks2; x1 += k0 + 5u;
#undef TFR
  *o0 = x0; *o1 = x1;
}

__device__ __forceinline__ uint32_t rand_bits32(uint32_t ka, uint32_t kb, uint32_t flat) {
  uint32_t a, b;
  threefry2x32(ka, kb, 0u, flat, &a, &b);
  return a ^ b;
}

__device__ __forceinline__ short f2bf(float f) {   // RNE fp32->bf16
  union { float f; uint32_t u; } c; c.f = f;
  uint32_t u = c.u;
  return (short)((u + 0x7FFFu + ((u >> 16) & 1u)) >> 16);
}

// raw barrier: LDS-only drain, no vmcnt(0)
__device__ __forceinline__ void bar_lds() {
  __asm__ __volatile__("s_waitcnt lgkmcnt(0)" ::: "memory");
  __builtin_amdgcn_s_barrier();
  __asm__ __volatile__("" ::: "memory");
}

// ---------------- K0: precompute bit-packed dropout masks [unchanged] ----------------
__global__ __launch_bounds__(256) void k_mask(uint32_t* __restrict__ M1w,
                                              uint32_t* __restrict__ M2w,
                                              uint32_t k1a, uint32_t k1b,
                                              uint32_t k2a, uint32_t k2b) {
  const int i = blockIdx.x * 256 + threadIdx.x;
  uint32_t ka, kb, base;
  uint32_t* dst;
  if (i < M1_WORDS) { ka = k1a; kb = k1b; base = (uint32_t)i * 32u; dst = M1w + i; }
  else { ka = k2a; kb = k2b; base = (uint32_t)(i - M1_WORDS) * 32u; dst = M2w + (i - M1_WORDS); }
  uint32_t w = 0u;
#pragma unroll
  for (int j = 0; j < 32; ++j) {
    uint32_t bits = rand_bits32(ka, kb, base + (uint32_t)j);
    w |= ((~bits) >> 31) << j;
  }
  *dst = w;
}

// ---------------- K0c: pre-convert w_ih -> bf16, zero-padded Wb[304][320] ----------
__global__ __launch_bounds__(256) void k_prepw(const float* __restrict__ w_ih,
                                               short* __restrict__ Wb) {
  int i8 = (blockIdx.x * 256 + threadIdx.x) * 8;   // 8 consecutive shorts
  if (i8 >= 304 * 320) return;
  short o[8];
#pragma unroll
  for (int j = 0; j < 8; ++j) {
    int pos = i8 + j;
    int n = pos / 320, k = pos - (pos / 320) * 320;
    float v = (n < 300 && k < 300) ? w_ih[(size_t)n * EMB + k] : 0.f;
    o[j] = f2bf(v);
  }
  *(s16x8*)(Wb + i8) = *(s16x8*)o;
}

// ---------------- K1 v7: MFMA GI GEMM — ONE block per s (no 3x redundancy) --------
// 512 blocks x 512 threads (8 waves). Tile 128(m=batch) x 304(n, 19 frags).
// Wave grid: wr = wave&1 (m-half), wc = wave>>1 (n-frags nt = wc + 4j, j<5).
// B comes pre-converted from Wb (pure 16B loads). K chunks of 32 (10 chunks).
__global__ __launch_bounds__(512) void k_gi7(const int* __restrict__ inputs,
                                             const float* __restrict__ emb,
                                             const short* __restrict__ Wb,
                                             const float* __restrict__ b_ih,
                                             const uint32_t* __restrict__ M1w,
                                             float* __restrict__ GI) {
  __shared__ short As[128 * 40];   // [b][k], stride 40 shorts = 80 B
  __shared__ short Bs[304 * 40];   // [n][k]
  __shared__ int idxs[128];
  const int t = threadIdx.x;
  const int s = blockIdx.x;
  const int lane = t & 63, wave = t >> 6;
  const int wr = wave & 1;         // m half (64 rows)
  const int wc = wave >> 1;        // n group: frags wc, wc+4, ...
  const int ml = lane & 15, quad = lane >> 4;
  const int arow = t >> 2;         // A staging row 0..127
  const int akq = t & 3;           // A staging k-slot

  if (t < 128) idxs[t] = inputs[t * SEQ + s];
  __syncthreads();

  const int nfr = (wc < 3) ? 5 : 4;   // frags per wave
  f32x4 acc[4][5];
#pragma unroll
  for (int i = 0; i < 4; ++i)
#pragma unroll
    for (int j = 0; j < 5; ++j) acc[i][j] = (f32x4){0.f, 0.f, 0.f, 0.f};

  const int myidx = idxs[arow];

  for (int c = 0; c < 10; ++c) {
    const int e0 = c * 32 + akq * 8;
    // ---- A: gather emb + dropout1 + bf16 (8 elements/thread) ----
    float xa[8];
#pragma unroll
    for (int j = 0; j < 8; ++j) xa[j] = 0.f;
    if (e0 + 7 < 300) {
#pragma unroll
      for (int q4 = 0; q4 < 2; ++q4) {
        float4 v = *(const float4*)(emb + (size_t)myidx * EMB + e0 + q4 * 4);
        xa[q4 * 4 + 0] = v.x; xa[q4 * 4 + 1] = v.y; xa[q4 * 4 + 2] = v.z; xa[q4 * 4 + 3] = v.w;
      }
    } else if (e0 < 300) {
#pragma unroll
      for (int j = 0; j < 8; ++j) {
        int e = e0 + j;
        if (e < 300) xa[j] = emb[(size_t)myidx * EMB + e];
      }
    }
    uint32_t mb = 0;
    if (e0 < 300) {
      uint32_t base = (uint32_t)((arow * SEQ + s) * EMB + e0);
      uint64_t mw = (uint64_t)M1w[base >> 5] | ((uint64_t)M1w[(base >> 5) + 1] << 32);
      mb = (uint32_t)(mw >> (base & 31));
    }
    short sa[8];
#pragma unroll
    for (int j = 0; j < 8; ++j)
      sa[j] = f2bf(((mb >> j) & 1u) ? xa[j] * 2.f : 0.f);
    // ---- B: pure 16B loads from Wb (1216 slots over 512 threads) ----
    s16x8 bv0, bv1, bv2;
    {
      int i0 = t;            // slots t, t+512, t+1024(<1216)
      int r0 = i0 >> 2, k0 = (i0 & 3) * 8;
      bv0 = *(const s16x8*)(Wb + (size_t)r0 * 320 + c * 32 + k0);
      int i1 = t + 512;
      int r1 = i1 >> 2, k1 = (i1 & 3) * 8;
      bv1 = *(const s16x8*)(Wb + (size_t)r1 * 320 + c * 32 + k1);
      if (t < 192) {
        int i2 = t + 1024;
        int r2 = i2 >> 2, k2 = (i2 & 3) * 8;
        bv2 = *(const s16x8*)(Wb + (size_t)r2 * 320 + c * 32 + k2);
      }
    }
    if (c > 0) __syncthreads();   // protect previous chunk's frag reads
    *(s16x8*)&As[arow * 40 + akq * 8] = *(s16x8*)&sa[0];
    {
      int i0 = t;       *(s16x8*)&Bs[(i0 >> 2) * 40 + (i0 & 3) * 8] = bv0;
      int i1 = t + 512; *(s16x8*)&Bs[(i1 >> 2) * 40 + (i1 & 3) * 8] = bv1;
      if (t < 192) { int i2 = t + 1024; *(s16x8*)&Bs[(i2 >> 2) * 40 + (i2 & 3) * 8] = bv2; }
    }
    __syncthreads();
    // ---- MFMA: 4 m-frags x nfr n-frags per wave ----
    s16x8 af[4];
#pragma unroll
    for (int mt = 0; mt < 4; ++mt)
      af[mt] = *(const s16x8*)&As[(wr * 64 + mt * 16 + ml) * 40 + quad * 8];
#pragma unroll
    for (int j = 0; j < 5; ++j) {
      if (j < nfr) {
        int nt = wc + 4 * j;
        s16x8 bf = *(const s16x8*)&Bs[(nt * 16 + ml) * 40 + quad * 8];
#pragma unroll
        for (int mt = 0; mt < 4; ++mt)
          acc[mt][j] = __builtin_amdgcn_mfma_f32_16x16x32_bf16(af[mt], bf, acc[mt][j], 0, 0, 0);
      }
    }
  }

  // ---- epilogue: C/D layout col=lane&15, row=quad*4+i ----
#pragma unroll
  for (int j = 0; j < 5; ++j) {
    if (j < nfr) {
      int n = (wc + 4 * j) * 16 + ml;
      if (n < 300) {
        float bias = b_ih[n];
#pragma unroll
        for (int mt = 0; mt < 4; ++mt) {
#pragma unroll
          for (int i = 0; i < 4; ++i) {
            int brow = wr * 64 + mt * 16 + quad * 4 + i;
            GI[(size_t)(s * BATCH + brow) * G3 + n] = acc[mt][j][i] + bias;
          }
        }
      }
    }
  }
}

// ---------------- K2 v8: best proven recurrence (~465 µs) [unchanged] ----------------
__global__ __launch_bounds__(1024, 4) void k_rnn8(const float* __restrict__ GI,
                                                  const float* __restrict__ w_hh,
                                                  const float* __restrict__ b_hh,
                                                  const uint8_t* __restrict__ M2,
                                                  float* __restrict__ Hd) {
  __shared__ float4 part[8][104];
  __shared__ float h_s[100];
  const int t = threadIdx.x, lane = t & 63, wave = t >> 6;
  const int q = wave >> 1, g = wave & 1;
  const int b = blockIdx.x;
  const int ulo = (lane < 36) ? lane : 35;
  const int u = g ? (64 + ulo) : lane;
  const bool dotstore = (g == 0) || (lane < 36);
  const int klo = (q < 4) ? q * 13 : 52 + (q - 4) * 12;

  const float* rowR = w_hh + (size_t)u * HID;
  const float* rowZ = w_hh + (size_t)(u + 100) * HID;
  const float* rowN = w_hh + (size_t)(u + 200) * HID;
  const float wr0 = rowR[klo + 0],  wr1 = rowR[klo + 1],  wr2 = rowR[klo + 2],
              wr3 = rowR[klo + 3],  wr4 = rowR[klo + 4],  wr5 = rowR[klo + 5],
              wr6 = rowR[klo + 6],  wr7 = rowR[klo + 7],  wr8 = rowR[klo + 8],
              wr9 = rowR[klo + 9],  wr10 = rowR[klo + 10], wr11 = rowR[klo + 11],
              wr12 = rowR[(klo + 12 < 100) ? (klo + 12) : 99];
  const float wz0 = rowZ[klo + 0],  wz1 = rowZ[klo + 1],  wz2 = rowZ[klo + 2],
              wz3 = rowZ[klo + 3],  wz4 = rowZ[klo + 4],  wz5 = rowZ[klo + 5],
              wz6 = rowZ[klo + 6],  wz7 = rowZ[klo + 7],  wz8 = rowZ[klo + 8],
              wz9 = rowZ[klo + 9],  wz10 = rowZ[klo + 10], wz11 = rowZ[klo + 11],
              wz12 = rowZ[(klo + 12 < 100) ? (klo + 12) : 99];
  const float wn0 = rowN[klo + 0],  wn1 = rowN[klo + 1],  wn2 = rowN[klo + 2],
              wn3 = rowN[klo + 3],  wn4 = rowN[klo + 4],  wn5 = rowN[klo + 5],
              wn6 = rowN[klo + 6],  wn7 = rowN[klo + 7],  wn8 = rowN[klo + 8],
              wn9 = rowN[klo + 9],  wn10 = rowN[klo + 10], wn11 = rowN[klo + 11],
              wn12 = rowN[(klo + 12 < 100) ? (klo + 12) : 99];

  const bool ew = (wave < 4) && (lane < 25);
  const int ue = wave * 25 + lane;
  float bR = 0.f, bZ = 0.f, bN = 0.f, gcR = 0.f, gcZ = 0.f, gcN = 0.f;
  uint8_t mc = 0;
  if (ew) {
    bR = b_hh[ue]; bZ = b_hh[100 + ue]; bN = b_hh[200 + ue];
    const float* g0 = GI + (size_t)b * G3;
    gcR = g0[ue]; gcZ = g0[100 + ue]; gcN = g0[200 + ue];
    mc = M2[(uint32_t)(b * HID + ue) >> 3];
  }

  if (t < 100) h_s[t] = 0.f;
  float hA = 0.f, hB = 0.f;
  __syncthreads();

#define RL(reg, L) __int_as_float(__builtin_amdgcn_readlane(__float_as_int(reg), (L)))
#define S1(HS, L, WR, WZ, WN) { float hk = RL(HS, L); \
    sR = fmaf(WR, hk, sR); sZ = fmaf(WZ, hk, sZ); sN = fmaf(WN, hk, sN); }
#define D12(HS, L0) \
  S1(HS, (L0) + 0,  wr0,  wz0,  wn0)  S1(HS, (L0) + 1,  wr1,  wz1,  wn1)  \
  S1(HS, (L0) + 2,  wr2,  wz2,  wn2)  S1(HS, (L0) + 3,  wr3,  wz3,  wn3)  \
  S1(HS, (L0) + 4,  wr4,  wz4,  wn4)  S1(HS, (L0) + 5,  wr5,  wz5,  wn5)  \
  S1(HS, (L0) + 6,  wr6,  wz6,  wn6)  S1(HS, (L0) + 7,  wr7,  wz7,  wn7)  \
  S1(HS, (L0) + 8,  wr8,  wz8,  wn8)  S1(HS, (L0) + 9,  wr9,  wz9,  wn9)  \
  S1(HS, (L0) + 10, wr10, wz10, wn10) S1(HS, (L0) + 11, wr11, wz11, wn11)
#define D13(HS, L0) D12(HS, L0) S1(HS, (L0) + 12, wr12, wz12, wn12)

  for (int s = 0; s < SEQ; ++s) {
    float gnR = 0.f, gnZ = 0.f, gnN = 0.f;
    uint8_t mn = 0;
    if (ew) {
      int sn = (s + 1 < SEQ) ? s + 1 : s;
      const float* gp = GI + (size_t)(sn * BATCH + b) * G3;
      gnR = gp[ue]; gnZ = gp[100 + ue]; gnN = gp[200 + ue];
      mn = M2[(uint32_t)((sn * BATCH + b) * HID + ue) >> 3];
    }

    float sR = 0.f, sZ = 0.f, sN = 0.f;
    switch (q) {
      case 0: { D13(hA, 0)  } break;
      case 1: { D13(hA, 13) } break;
      case 2: { D13(hA, 26) } break;
      case 3: { D13(hA, 39) } break;
      case 4: { D12(hA, 52) } break;
      case 5: { D12(hB, 0)  } break;
      case 6: { D12(hB, 12) } break;
      case 7: { D12(hB, 24) } break;
    }
    if (dotstore) part[q][u] = make_float4(sR, sZ, sN, 0.f);
    bar_lds();   // barrier 1: LDS drain only

    if (wave < 4) {
      if (lane < 25) {
        float4 p0 = part[0][ue], p1 = part[1][ue], p2 = part[2][ue], p3 = part[3][ue];
        float4 p4 = part[4][ue], p5 = part[5][ue], p6 = part[6][ue], p7 = part[7][ue];
        float hr = ((p0.x + p1.x) + (p2.x + p3.x)) + ((p4.x + p5.x) + (p6.x + p7.x)) + bR;
        float hz = ((p0.y + p1.y) + (p2.y + p3.y)) + ((p4.y + p5.y) + (p6.y + p7.y)) + bZ;
        float hn = ((p0.z + p1.z) + (p2.z + p3.z)) + ((p4.z + p5.z) + (p6.z + p7.z)) + bN;
        float r = 1.f / (1.f + __expf(-(gcR + hr)));
        float z = 1.f / (1.f + __expf(-(gcZ + hz)));
        float xn = gcN + r * hn;
        float e2 = __expf(2.f * fabsf(xn));
        float n = copysignf(1.f - 2.f / (e2 + 1.f), xn);
        float hprev = h_s[ue];
        float hnew = (1.f - z) * n + z * hprev;
        uint32_t fl = (uint32_t)((s * BATCH + b) * HID + ue);
        float hd = ((mc >> (fl & 7)) & 1) ? hnew * 2.f : 0.f;
        Hd[(size_t)(b * SEQ + s) * HID + ue] = hd;
        h_s[ue] = hnew;
      }
    }
    bar_lds();   // barrier 2: LDS drain only
    hA = h_s[lane];
    hB = h_s[64 + ulo];
    gcR = gnR; gcZ = gnZ; gcN = gnN; mc = mn;
  }
#undef D13
#undef D12
#undef S1
#undef RL
}

// ---------------- K3: logits + log_softmax [unchanged] ----------------
__global__ __launch_bounds__(64) void k_out(const float* __restrict__ Hd,
                                            const float* __restrict__ w_lin,
                                            const float* __restrict__ b_lin,
                                            float* __restrict__ out) {
  __shared__ float Wl[NCLS * HID];
  __shared__ float bl[NCLS];
  const int t = threadIdx.x;
  for (int i = t; i < NCLS * HID; i += 64) Wl[i] = w_lin[i];
  if (t < NCLS) bl[t] = b_lin[t];
  __syncthreads();

  const int r0 = (blockIdx.x * 64 + t) * 4;
  float acc[4][NCLS];
#pragma unroll
  for (int r = 0; r < 4; ++r)
#pragma unroll
    for (int c = 0; c < NCLS; ++c) acc[r][c] = bl[c];

  for (int k = 0; k < HID; k += 4) {
    float4 h0 = *(const float4*)(Hd + (size_t)(r0 + 0) * HID + k);
    float4 h1 = *(const float4*)(Hd + (size_t)(r0 + 1) * HID + k);
    float4 h2 = *(const float4*)(Hd + (size_t)(r0 + 2) * HID + k);
    float4 h3 = *(const float4*)(Hd + (size_t)(r0 + 3) * HID + k);
#pragma unroll
    for (int c = 0; c < NCLS; ++c) {
      float4 w4 = *(const float4*)&Wl[c * HID + k];
      acc[0][c] += h0.x * w4.x + h0.y * w4.y + h0.z * w4.z + h0.w * w4.w;
      acc[1][c] += h1.x * w4.x + h1.y * w4.y + h1.z * w4.z + h1.w * w4.w;
      acc[2][c] += h2.x * w4.x + h2.y * w4.y + h2.z * w4.z + h2.w * w4.w;
      acc[3][c] += h3.x * w4.x + h3.y * w4.y + h3.z * w4.z + h3.w * w4.w;
    }
  }

  float lse[4];
#pragma unroll
  for (int r = 0; r < 4; ++r) {
    float mx = acc[r][0];
#pragma unroll
    for (int c = 1; c < NCLS; ++c) mx = fmaxf(mx, acc[r][c]);
    float se = 0.f;
#pragma unroll
    for (int c = 0; c < NCLS; ++c) se += __expf(acc[r][c] - mx);
    lse[r] = mx + __logf(se);
  }
  const int b = r0 >> 9, s0 = r0 & 511;
#pragma unroll
  for (int c = 0; c < NCLS; ++c) {
    float4 o = make_float4(acc[0][c] - lse[0], acc[1][c] - lse[1],
                           acc[2][c] - lse[2], acc[3][c] - lse[3]);
    *(float4*)(out + (size_t)(b * NCLS + c) * SEQ + s0) = o;
  }
}

// ---------------- host ----------------
extern "C" void kernel_launch(void* const* d_in, const int* in_sizes, int n_in,
                              void* d_out, int out_size, void* d_ws, size_t ws_size,
                              hipStream_t stream) {
  const int*   inputs = (const int*)d_in[0];
  const float* emb    = (const float*)d_in[1];
  const float* w_ih   = (const float*)d_in[2];
  const float* w_hh   = (const float*)d_in[3];
  const float* b_ih   = (const float*)d_in[4];
  const float* b_hh   = (const float*)d_in[5];
  const float* w_lin  = (const float*)d_in[6];
  const float* b_lin  = (const float*)d_in[7];
  float* out = (float*)d_out;

  float* GI = (float*)d_ws;                           // 78.6 MB
  float* Hd = GI + (size_t)NROWS * G3;                // 26.2 MB
  uint8_t* M1 = (uint8_t*)(Hd + (size_t)NROWS * HID); // 2.46 MB
  uint8_t* M2 = M1 + (size_t)M1_WORDS * 4;            // 0.82 MB
  short* Wb = (short*)(M2 + (size_t)M2_WORDS * 4);    // 304*320*2 = 190 KB

  uint32_t dk1a, dk1b, dk2a, dk2b;
  threefry2x32(0u, 42u, 0u, 0u, &dk1a, &dk1b);
  threefry2x32(0u, 42u, 0u, 1u, &dk2a, &dk2b);

  k_mask<<<(M1_WORDS + M2_WORDS) / 256, 256, 0, stream>>>(
      (uint32_t*)M1, (uint32_t*)M2, dk1a, dk1b, dk2a, dk2b);
  k_prepw<<<(304 * 320 / 8 + 255) / 256, 256, 0, stream>>>(w_ih, Wb);
  k_gi7<<<512, 512, 0, stream>>>(inputs, emb, Wb, b_ih, (const uint32_t*)M1, GI);
  k_rnn8<<<BATCH, 1024, 0, stream>>>(GI, w_hh, b_hh, M2, Hd);
  k_out<<<256, 64, 0, stream>>>(Hd, w_lin, b_lin, out);
}

// Round 14
// 618.321 us; speedup vs baseline: 2.4282x; 1.1335x over previous
//
#include <hip/hip_runtime.h>
#include <hip/hip_bf16.h>
#include <cstdint>

#define BATCH 128
#define SEQ   512
#define EMB   300
#define HID   100
#define G3    300
#define NCLS  20
#define NROWS (SEQ * BATCH)

#define M1_WORDS 614400   // 128*512*300 / 32
#define M2_WORDS 204800   // 512*128*100 / 32

typedef __attribute__((ext_vector_type(4))) float f32x4;
typedef __attribute__((ext_vector_type(8))) short s16x8;
typedef __fp16 h16x2 __attribute__((ext_vector_type(2)));   // matches cvt_pkrtz return

// ---------------- threefry2x32 (JAX-compatible, verified round 1) ----------------
__host__ __device__ __forceinline__ void threefry2x32(uint32_t k0, uint32_t k1,
                                                      uint32_t x0, uint32_t x1,
                                                      uint32_t* o0, uint32_t* o1) {
  uint32_t ks2 = k0 ^ k1 ^ 0x1BD11BDAu;
  x0 += k0; x1 += k1;
#define TFR(r) { x0 += x1; x1 = (x1 << (r)) | (x1 >> (32 - (r))); x1 ^= x0; }
  TFR(13) TFR(15) TFR(26) TFR(6)  x0 += k1;  x1 += ks2 + 1u;
  TFR(17) TFR(29) TFR(16) TFR(24) x0 += ks2; x1 += k0 + 2u;
  TFR(13) TFR(15) TFR(26) TFR(6)  x0 += k0;  x1 += k1 + 3u;
  TFR(17) TFR(29) TFR(16) TFR(24) x0 += k1;  x1 += ks2 + 4u;
  TFR(13) TFR(15) TFR(26) TFR(6)  x0 += ks2; x1 += k0 + 5u;
#undef TFR
  *o0 = x0; *o1 = x1;
}

__device__ __forceinline__ uint32_t rand_bits32(uint32_t ka, uint32_t kb, uint32_t flat) {
  uint32_t a, b;
  threefry2x32(ka, kb, 0u, flat, &a, &b);
  return a ^ b;
}

__device__ __forceinline__ short f2bf(float f) {   // RNE fp32->bf16
  union { float f; uint32_t u; } c; c.f = f;
  uint32_t u = c.u;
  return (short)((u + 0x7FFFu + ((u >> 16) & 1u)) >> 16);
}

// raw barrier: LDS-only drain, no vmcnt(0)
__device__ __forceinline__ void bar_lds() {
  __asm__ __volatile__("s_waitcnt lgkmcnt(0)" ::: "memory");
  __builtin_amdgcn_s_barrier();
  __asm__ __volatile__("" ::: "memory");
}

// ---------------- K0: precompute bit-packed dropout masks [unchanged] ----------------
__global__ __launch_bounds__(256) void k_mask(uint32_t* __restrict__ M1w,
                                              uint32_t* __restrict__ M2w,
                                              uint32_t k1a, uint32_t k1b,
                                              uint32_t k2a, uint32_t k2b) {
  const int i = blockIdx.x * 256 + threadIdx.x;
  uint32_t ka, kb, base;
  uint32_t* dst;
  if (i < M1_WORDS) { ka = k1a; kb = k1b; base = (uint32_t)i * 32u; dst = M1w + i; }
  else { ka = k2a; kb = k2b; base = (uint32_t)(i - M1_WORDS) * 32u; dst = M2w + (i - M1_WORDS); }
  uint32_t w = 0u;
#pragma unroll
  for (int j = 0; j < 32; ++j) {
    uint32_t bits = rand_bits32(ka, kb, base + (uint32_t)j);
    w |= ((~bits) >> 31) << j;
  }
  *dst = w;
}

// ---------------- K0c: pre-convert w_ih -> bf16, zero-padded Wb[304][320] ----------
__global__ __launch_bounds__(256) void k_prepw(const float* __restrict__ w_ih,
                                               short* __restrict__ Wb) {
  int i8 = (blockIdx.x * 256 + threadIdx.x) * 8;
  if (i8 >= 304 * 320) return;
  short o[8];
#pragma unroll
  for (int j = 0; j < 8; ++j) {
    int pos = i8 + j;
    int n = pos / 320, k = pos - (pos / 320) * 320;
    float v = (n < 300 && k < 300) ? w_ih[(size_t)n * EMB + k] : 0.f;
    o[j] = f2bf(v);
  }
  *(s16x8*)(Wb + i8) = *(s16x8*)o;
}

// ---------------- K1 v7: MFMA GI GEMM, one block per s [unchanged] ----------------
__global__ __launch_bounds__(512) void k_gi7(const int* __restrict__ inputs,
                                             const float* __restrict__ emb,
                                             const short* __restrict__ Wb,
                                             const float* __restrict__ b_ih,
                                             const uint32_t* __restrict__ M1w,
                                             float* __restrict__ GI) {
  __shared__ short As[128 * 40];
  __shared__ short Bs[304 * 40];
  __shared__ int idxs[128];
  const int t = threadIdx.x;
  const int s = blockIdx.x;
  const int lane = t & 63, wave = t >> 6;
  const int wr = wave & 1;
  const int wc = wave >> 1;
  const int ml = lane & 15, quad = lane >> 4;
  const int arow = t >> 2;
  const int akq = t & 3;

  if (t < 128) idxs[t] = inputs[t * SEQ + s];
  __syncthreads();

  const int nfr = (wc < 3) ? 5 : 4;
  f32x4 acc[4][5];
#pragma unroll
  for (int i = 0; i < 4; ++i)
#pragma unroll
    for (int j = 0; j < 5; ++j) acc[i][j] = (f32x4){0.f, 0.f, 0.f, 0.f};

  const int myidx = idxs[arow];

  for (int c = 0; c < 10; ++c) {
    const int e0 = c * 32 + akq * 8;
    float xa[8];
#pragma unroll
    for (int j = 0; j < 8; ++j) xa[j] = 0.f;
    if (e0 + 7 < 300) {
#pragma unroll
      for (int q4 = 0; q4 < 2; ++q4) {
        float4 v = *(const float4*)(emb + (size_t)myidx * EMB + e0 + q4 * 4);
        xa[q4 * 4 + 0] = v.x; xa[q4 * 4 + 1] = v.y; xa[q4 * 4 + 2] = v.z; xa[q4 * 4 + 3] = v.w;
      }
    } else if (e0 < 300) {
#pragma unroll
      for (int j = 0; j < 8; ++j) {
        int e = e0 + j;
        if (e < 300) xa[j] = emb[(size_t)myidx * EMB + e];
      }
    }
    uint32_t mb = 0;
    if (e0 < 300) {
      uint32_t base = (uint32_t)((arow * SEQ + s) * EMB + e0);
      uint64_t mw = (uint64_t)M1w[base >> 5] | ((uint64_t)M1w[(base >> 5) + 1] << 32);
      mb = (uint32_t)(mw >> (base & 31));
    }
    short sa[8];
#pragma unroll
    for (int j = 0; j < 8; ++j)
      sa[j] = f2bf(((mb >> j) & 1u) ? xa[j] * 2.f : 0.f);
    s16x8 bv0, bv1, bv2;
    {
      int i0 = t;
      bv0 = *(const s16x8*)(Wb + (size_t)(i0 >> 2) * 320 + c * 32 + (i0 & 3) * 8);
      int i1 = t + 512;
      bv1 = *(const s16x8*)(Wb + (size_t)(i1 >> 2) * 320 + c * 32 + (i1 & 3) * 8);
      if (t < 192) {
        int i2 = t + 1024;
        bv2 = *(const s16x8*)(Wb + (size_t)(i2 >> 2) * 320 + c * 32 + (i2 & 3) * 8);
      }
    }
    if (c > 0) __syncthreads();
    *(s16x8*)&As[arow * 40 + akq * 8] = *(s16x8*)&sa[0];
    {
      int i0 = t;       *(s16x8*)&Bs[(i0 >> 2) * 40 + (i0 & 3) * 8] = bv0;
      int i1 = t + 512; *(s16x8*)&Bs[(i1 >> 2) * 40 + (i1 & 3) * 8] = bv1;
      if (t < 192) { int i2 = t + 1024; *(s16x8*)&Bs[(i2 >> 2) * 40 + (i2 & 3) * 8] = bv2; }
    }
    __syncthreads();
    s16x8 af[4];
#pragma unroll
    for (int mt = 0; mt < 4; ++mt)
      af[mt] = *(const s16x8*)&As[(wr * 64 + mt * 16 + ml) * 40 + quad * 8];
#pragma unroll
    for (int j = 0; j < 5; ++j) {
      if (j < nfr) {
        int nt = wc + 4 * j;
        s16x8 bf = *(const s16x8*)&Bs[(nt * 16 + ml) * 40 + quad * 8];
#pragma unroll
        for (int mt = 0; mt < 4; ++mt)
          acc[mt][j] = __builtin_amdgcn_mfma_f32_16x16x32_bf16(af[mt], bf, acc[mt][j], 0, 0, 0);
      }
    }
  }

#pragma unroll
  for (int j = 0; j < 5; ++j) {
    if (j < nfr) {
      int n = (wc + 4 * j) * 16 + ml;
      if (n < 300) {
        float bias = b_ih[n];
#pragma unroll
        for (int mt = 0; mt < 4; ++mt) {
#pragma unroll
          for (int i = 0; i < 4; ++i) {
            int brow = wr * 64 + mt * 16 + quad * 4 + i;
            GI[(size_t)(s * BATCH + brow) * G3 + n] = acc[mt][j][i] + bias;
          }
        }
      }
    }
  }
}

// ---------------- K2 v10: 8 waves + packed-f16 v_dot2 dot ----------------
// 128 blocks x 512 threads. g = wave&1 (unit group), q = wave>>1 (4 pair-slices
// of the 50 k-pairs: 13/13/12/12). Weights: 39 resident half2 (f16 pairs).
// h broadcast: ONE packed register hP (pair p in lane p, p<50); readlane + fdot2.
__global__ __launch_bounds__(512, 1) void k_rnn10(const float* __restrict__ GI,
                                                  const float* __restrict__ w_hh,
                                                  const float* __restrict__ b_hh,
                                                  const uint8_t* __restrict__ M2,
                                                  float* __restrict__ Hd) {
  __shared__ float4 part[4][104];
  __shared__ __align__(8) float h_s[100];
  const int t = threadIdx.x, lane = t & 63, wave = t >> 6;
  const int q = wave >> 1, g = wave & 1;
  const int b = blockIdx.x;
  const int ulo = (lane < 36) ? lane : 35;
  const int u = g ? (64 + ulo) : lane;
  const bool dotstore = (g == 0) || (lane < 36);
  const int kplo = (q < 2) ? q * 13 : 26 + (q - 2) * 12;   // pair base

  const float* rowR = w_hh + (size_t)u * HID;
  const float* rowZ = w_hh + (size_t)(u + 100) * HID;
  const float* rowN = w_hh + (size_t)(u + 200) * HID;
  // pair offsets (floats); slot 12 clamped in-bounds (only q<2 uses its value)
  const int o12 = (kplo + 12 < 50) ? 2 * (kplo + 12) : 96;
#define PK(row, off) __builtin_amdgcn_cvt_pkrtz((row)[off], (row)[(off) + 1])
  const h16x2 wr0 = PK(rowR, 2 * kplo + 0),  wr1 = PK(rowR, 2 * kplo + 2),
              wr2 = PK(rowR, 2 * kplo + 4),  wr3 = PK(rowR, 2 * kplo + 6),
              wr4 = PK(rowR, 2 * kplo + 8),  wr5 = PK(rowR, 2 * kplo + 10),
              wr6 = PK(rowR, 2 * kplo + 12), wr7 = PK(rowR, 2 * kplo + 14),
              wr8 = PK(rowR, 2 * kplo + 16), wr9 = PK(rowR, 2 * kplo + 18),
              wr10 = PK(rowR, 2 * kplo + 20), wr11 = PK(rowR, 2 * kplo + 22),
              wr12 = PK(rowR, o12);
  const h16x2 wz0 = PK(rowZ, 2 * kplo + 0),  wz1 = PK(rowZ, 2 * kplo + 2),
              wz2 = PK(rowZ, 2 * kplo + 4),  wz3 = PK(rowZ, 2 * kplo + 6),
              wz4 = PK(rowZ, 2 * kplo + 8),  wz5 = PK(rowZ, 2 * kplo + 10),
              wz6 = PK(rowZ, 2 * kplo + 12), wz7 = PK(rowZ, 2 * kplo + 14),
              wz8 = PK(rowZ, 2 * kplo + 16), wz9 = PK(rowZ, 2 * kplo + 18),
              wz10 = PK(rowZ, 2 * kplo + 20), wz11 = PK(rowZ, 2 * kplo + 22),
              wz12 = PK(rowZ, o12);
  const h16x2 wn0 = PK(rowN, 2 * kplo + 0),  wn1 = PK(rowN, 2 * kplo + 2),
              wn2 = PK(rowN, 2 * kplo + 4),  wn3 = PK(rowN, 2 * kplo + 6),
              wn4 = PK(rowN, 2 * kplo + 8),  wn5 = PK(rowN, 2 * kplo + 10),
              wn6 = PK(rowN, 2 * kplo + 12), wn7 = PK(rowN, 2 * kplo + 14),
              wn8 = PK(rowN, 2 * kplo + 16), wn9 = PK(rowN, 2 * kplo + 18),
              wn10 = PK(rowN, 2 * kplo + 20), wn11 = PK(rowN, 2 * kplo + 22),
              wn12 = PK(rowN, o12);
#undef PK

  const bool ew = (wave < 4) && (lane < 25);
  const int ue = wave * 25 + lane;   // 0..99 when ew
  float bR = 0.f, bZ = 0.f, bN = 0.f, gcR = 0.f, gcZ = 0.f, gcN = 0.f;
  uint8_t mc = 0;
  if (ew) {
    bR = b_hh[ue]; bZ = b_hh[100 + ue]; bN = b_hh[200 + ue];
    const float* g0 = GI + (size_t)b * G3;
    gcR = g0[ue]; gcZ = g0[100 + ue]; gcN = g0[200 + ue];
    mc = M2[(uint32_t)(b * HID + ue) >> 3];
  }

  if (t < 100) h_s[t] = 0.f;
  h16x2 hP = (h16x2){(__fp16)0.f, (__fp16)0.f};
  const int pl = (lane < 50) ? lane : 49;   // this lane's h pair
  __syncthreads();

#define RLP(L) __builtin_bit_cast(h16x2, __builtin_amdgcn_readlane(__builtin_bit_cast(int, hP), (L)))
#define S1P(J, L) { h16x2 hh = RLP(L); \
    sR = __builtin_amdgcn_fdot2(wr##J, hh, sR, false); \
    sZ = __builtin_amdgcn_fdot2(wz##J, hh, sZ, false); \
    sN = __builtin_amdgcn_fdot2(wn##J, hh, sN, false); }
#define DOT12(L0) \
  S1P(0, (L0) + 0)  S1P(1, (L0) + 1)  S1P(2, (L0) + 2)  S1P(3, (L0) + 3)  \
  S1P(4, (L0) + 4)  S1P(5, (L0) + 5)  S1P(6, (L0) + 6)  S1P(7, (L0) + 7)  \
  S1P(8, (L0) + 8)  S1P(9, (L0) + 9)  S1P(10, (L0) + 10) S1P(11, (L0) + 11)
#define DOT13(L0) DOT12(L0) S1P(12, (L0) + 12)

  for (int s = 0; s < SEQ; ++s) {
    // prefetch next step's gi + mask byte (consumed next iteration)
    float gnR = 0.f, gnZ = 0.f, gnN = 0.f;
    uint8_t mn = 0;
    if (ew) {
      int sn = (s + 1 < SEQ) ? s + 1 : s;
      const float* gp = GI + (size_t)(sn * BATCH + b) * G3;
      gnR = gp[ue]; gnZ = gp[100 + ue]; gnN = gp[200 + ue];
      mn = M2[(uint32_t)((sn * BATCH + b) * HID + ue) >> 3];
    }

    float sR = 0.f, sZ = 0.f, sN = 0.f;
    switch (q) {   // wave-uniform; readlane indices are literals
      case 0: { DOT13(0)  } break;
      case 1: { DOT13(13) } break;
      case 2: { DOT12(26) } break;
      case 3: { DOT12(38) } break;
    }
    if (dotstore) part[q][u] = make_float4(sR, sZ, sN, 0.f);
    bar_lds();   // barrier 1: partials visible (LDS-only)

    if (wave < 4) {
      if (lane < 25) {
        float4 p0 = part[0][ue], p1 = part[1][ue], p2 = part[2][ue], p3 = part[3][ue];
        float hr = (p0.x + p1.x) + (p2.x + p3.x) + bR;
        float hz = (p0.y + p1.y) + (p2.y + p3.y) + bZ;
        float hn = (p0.z + p1.z) + (p2.z + p3.z) + bN;
        float r = 1.f / (1.f + __expf(-(gcR + hr)));
        float z = 1.f / (1.f + __expf(-(gcZ + hz)));
        float xn = gcN + r * hn;
        float e2 = __expf(2.f * fabsf(xn));
        float n = copysignf(1.f - 2.f / (e2 + 1.f), xn);   // overflow-safe tanh
        float hprev = h_s[ue];
        float hnew = (1.f - z) * n + z * hprev;
        uint32_t fl = (uint32_t)((s * BATCH + b) * HID + ue);
        float hd = ((mc >> (fl & 7)) & 1) ? hnew * 2.f : 0.f;
        Hd[(size_t)(b * SEQ + s) * HID + ue] = hd;   // store stays in flight
        h_s[ue] = hnew;
      }
    }
    bar_lds();   // barrier 2: h_s updated
    {
      float2 hp2 = *(const float2*)&h_s[2 * pl];    // b64, 8-aligned
      hP = __builtin_amdgcn_cvt_pkrtz(hp2.x, hp2.y);
    }
    gcR = gnR; gcZ = gnZ; gcN = gnN; mc = mn;
  }
#undef DOT13
#undef DOT12
#undef S1P
#undef RLP
}

// ---------------- K3: logits + log_softmax [unchanged] ----------------
__global__ __launch_bounds__(64) void k_out(const float* __restrict__ Hd,
                                            const float* __restrict__ w_lin,
                                            const float* __restrict__ b_lin,
                                            float* __restrict__ out) {
  __shared__ float Wl[NCLS * HID];
  __shared__ float bl[NCLS];
  const int t = threadIdx.x;
  for (int i = t; i < NCLS * HID; i += 64) Wl[i] = w_lin[i];
  if (t < NCLS) bl[t] = b_lin[t];
  __syncthreads();

  const int r0 = (blockIdx.x * 64 + t) * 4;
  float acc[4][NCLS];
#pragma unroll
  for (int r = 0; r < 4; ++r)
#pragma unroll
    for (int c = 0; c < NCLS; ++c) acc[r][c] = bl[c];

  for (int k = 0; k < HID; k += 4) {
    float4 h0 = *(const float4*)(Hd + (size_t)(r0 + 0) * HID + k);
    float4 h1 = *(const float4*)(Hd + (size_t)(r0 + 1) * HID + k);
    float4 h2 = *(const float4*)(Hd + (size_t)(r0 + 2) * HID + k);
    float4 h3 = *(const float4*)(Hd + (size_t)(r0 + 3) * HID + k);
#pragma unroll
    for (int c = 0; c < NCLS; ++c) {
      float4 w4 = *(const float4*)&Wl[c * HID + k];
      acc[0][c] += h0.x * w4.x + h0.y * w4.y + h0.z * w4.z + h0.w * w4.w;
      acc[1][c] += h1.x * w4.x + h1.y * w4.y + h1.z * w4.z + h1.w * w4.w;
      acc[2][c] += h2.x * w4.x + h2.y * w4.y + h2.z * w4.z + h2.w * w4.w;
      acc[3][c] += h3.x * w4.x + h3.y * w4.y + h3.z * w4.z + h3.w * w4.w;
    }
  }

  float lse[4];
#pragma unroll
  for (int r = 0; r < 4; ++r) {
    float mx = acc[r][0];
#pragma unroll
    for (int c = 1; c < NCLS; ++c) mx = fmaxf(mx, acc[r][c]);
    float se = 0.f;
#pragma unroll
    for (int c = 0; c < NCLS; ++c) se += __expf(acc[r][c] - mx);
    lse[r] = mx + __logf(se);
  }
  const int b = r0 >> 9, s0 = r0 & 511;
#pragma unroll
  for (int c = 0; c < NCLS; ++c) {
    float4 o = make_float4(acc[0][c] - lse[0], acc[1][c] - lse[1],
                           acc[2][c] - lse[2], acc[3][c] - lse[3]);
    *(float4*)(out + (size_t)(b * NCLS + c) * SEQ + s0) = o;
  }
}

// ---------------- host ----------------
extern "C" void kernel_launch(void* const* d_in, const int* in_sizes, int n_in,
                              void* d_out, int out_size, void* d_ws, size_t ws_size,
                              hipStream_t stream) {
  const int*   inputs = (const int*)d_in[0];
  const float* emb    = (const float*)d_in[1];
  const float* w_ih   = (const float*)d_in[2];
  const float* w_hh   = (const float*)d_in[3];
  const float* b_ih   = (const float*)d_in[4];
  const float* b_hh   = (const float*)d_in[5];
  const float* w_lin  = (const float*)d_in[6];
  const float* b_lin  = (const float*)d_in[7];
  float* out = (float*)d_out;

  float* GI = (float*)d_ws;                           // 78.6 MB
  float* Hd = GI + (size_t)NROWS * G3;                // 26.2 MB
  uint8_t* M1 = (uint8_t*)(Hd + (size_t)NROWS * HID); // 2.46 MB
  uint8_t* M2 = M1 + (size_t)M1_WORDS * 4;            // 0.82 MB
  short* Wb = (short*)(M2 + (size_t)M2_WORDS * 4);    // 190 KB

  uint32_t dk1a, dk1b, dk2a, dk2b;
  threefry2x32(0u, 42u, 0u, 0u, &dk1a, &dk1b);
  threefry2x32(0u, 42u, 0u, 1u, &dk2a, &dk2b);

  k_mask<<<(M1_WORDS + M2_WORDS) / 256, 256, 0, stream>>>(
      (uint32_t*)M1, (uint32_t*)M2, dk1a, dk1b, dk2a, dk2b);
  k_prepw<<<(304 * 320 / 8 + 255) / 256, 256, 0, stream>>>(w_ih, Wb);
  k_gi7<<<512, 512, 0, stream>>>(inputs, emb, Wb, b_ih, (const uint32_t*)M1, GI);
  k_rnn10<<<BATCH, 512, 0, stream>>>(GI, w_hh, b_hh, M2, Hd);
  k_out<<<256, 64, 0, stream>>>(Hd, w_lin, b_lin, out);
}